// Round 6
// baseline (410.140 us; speedup 1.0000x reference)
//
#include <hip/hip_runtime.h>
#include <stdint.h>

// out[t, :] = W[:, ids[t]]
// Loop inversion: bucket tokens by vocab window of 256; stream W coalesced
// exactly once; emit per-token rows. Round 6: intra-block double-buffered
// pipeline using async global_load_lds (size=4; W rows are only 4B-aligned)
// so stage(c+1) is in flight during emit(c) — kills the stage/emit phase
// serialization that held emit at ~100us (round 4/5 evidence).
#define VOCAB   50257
#define DMODEL  1024
#define VWIN    256
#define NB      ((VOCAB + VWIN - 1) / VWIN)   // 197
#define DCHUNK  32
#define NCHUNK  8                              // chunks per block: 8*32 = 256 d
#define HBLK    16
#define NTOT    (NB * HBLK)                    // 3152

// ws layout (int32):
//   [0..4095]      counts[bucket*16 + blk]
//   [4096..8191]   start (exclusive scan, NTOT+1 used)
//   [8192..]       perm  (packed (id<<16)|t, grouped by bucket)
#define WS_COUNT  0
#define WS_START  4096
#define WS_PERM   8192

typedef __attribute__((address_space(1))) const void glb_cv;
typedef __attribute__((address_space(3))) void lds_v;

__global__ __launch_bounds__(256) void hist_kernel(
    const int* __restrict__ ids, int* __restrict__ ws, int n_tokens)
{
    __shared__ int h[NB];
    const int tid = threadIdx.x, blk = blockIdx.x;
    for (int i = tid; i < NB; i += 256) h[i] = 0;
    __syncthreads();
    const int per = (n_tokens + HBLK - 1) / HBLK;
    const int t0 = blk * per;
    const int t1 = min(n_tokens, t0 + per);
    for (int t = t0 + tid; t < t1; t += 256)
        atomicAdd(&h[ids[t] >> 8], 1);            // LDS atomic
    __syncthreads();
    for (int i = tid; i < NB; i += 256)
        ws[WS_COUNT + i * HBLK + blk] = h[i];
}

__global__ __launch_bounds__(256) void scan_kernel(int* __restrict__ ws)
{
    __shared__ int s[256];
    const int tid = threadIdx.x;
    const int CH = (NTOT + 255) / 256;            // 13
    const int base = tid * CH;
    int vals[(NTOT + 255) / 256];
    int sum = 0;
#pragma unroll
    for (int j = 0; j < CH; j++) {
        int idx = base + j;
        int v = (idx < NTOT) ? ws[WS_COUNT + idx] : 0;
        vals[j] = v; sum += v;
    }
    s[tid] = sum;
    __syncthreads();
    for (int off = 1; off < 256; off <<= 1) {
        int v = (tid >= off) ? s[tid - off] : 0;
        __syncthreads();
        s[tid] += v;
        __syncthreads();
    }
    int run = (tid > 0) ? s[tid - 1] : 0;
#pragma unroll
    for (int j = 0; j < CH; j++) {
        int idx = base + j;
        if (idx < NTOT) ws[WS_START + idx] = run;
        run += vals[j];
    }
    if (tid == 255) ws[WS_START + NTOT] = run;
}

__global__ __launch_bounds__(256) void scatter_kernel(
    const int* __restrict__ ids, int* __restrict__ ws, int n_tokens)
{
    __shared__ int cur[NB];
    const int tid = threadIdx.x, blk = blockIdx.x;
    for (int i = tid; i < NB; i += 256)
        cur[i] = ws[WS_START + i * HBLK + blk];
    __syncthreads();
    const int per = (n_tokens + HBLK - 1) / HBLK;
    const int t0 = blk * per;
    const int t1 = min(n_tokens, t0 + per);
    for (int t = t0 + tid; t < t1; t += 256) {
        int id = ids[t];
        int b  = id >> 8;
        int pos = atomicAdd(&cur[b], 1);          // LDS atomic
        ws[WS_PERM + pos] = (int)(((uint32_t)id << 16) | (uint32_t)t);
    }
}

__global__ __launch_bounds__(256) void emit_kernel(
    const float* __restrict__ W, const int* __restrict__ ws,
    float* __restrict__ out)
{
    __shared__ float tile[2][DCHUNK][VWIN + 1];   // 2 x 32.9 KB

    const int vwin = blockIdx.x;           // 0..196
    const int q    = blockIdx.y;           // 0..3 (d-quarter of 256)
    const int v0   = vwin << 8;
    const int tid  = threadIdx.x;
    const int lane = tid & 63;
    const int w    = tid >> 6;             // wave 0..3

    const int begin = ws[WS_START + vwin * HBLK];
    const int end   = ws[WS_START + (vwin + 1) * HBLK];

    const int g    = lane >> 3;            // token slot 0..7
    const int dsub = (lane & 7) << 2;      // 0,4,..,28

    // async stage of chunk c into buffer b: wave w loads rows w*8..w*8+7,
    // each row as 4 segments of 64 floats (256B, 4B-aligned always).
    auto stage_async = [&](int c, int b) {
        const int dbase = q * 256 + c * DCHUNK;
        const float* rowbase = W + (size_t)(dbase + w * 8) * VOCAB + v0;
#pragma unroll
        for (int rr = 0; rr < 8; rr++) {
            const float* rowp = rowbase + (size_t)rr * VOCAB;
#pragma unroll
            for (int qq = 0; qq < 4; qq++) {
                __builtin_amdgcn_global_load_lds(
                    (glb_cv*)(rowp + qq * 64 + lane),
                    (lds_v*)&tile[b][w * 8 + rr][qq * 64],
                    4, 0, 0);
            }
        }
    };

    auto emit_chunk = [&](int c, int b) {
        const int dout = q * 256 + c * DCHUNK;
        for (int i = begin + w * 8; i < end; i += 32) {
            int idx = i + g;
            if (idx < end) {
                uint32_t packed = (uint32_t)ws[WS_PERM + idx];
                int t   = (int)(packed & 0xFFFFu);
                int col = (int)(packed >> 16) - v0;
                float4 v;
                v.x = tile[b][dsub][col];
                v.y = tile[b][dsub + 1][col];
                v.z = tile[b][dsub + 2][col];
                v.w = tile[b][dsub + 3][col];
                *(float4*)(out + (size_t)t * DMODEL + dout + dsub) = v;
            }
        }
    };

    if (vwin < NB - 1) {
        // Pipelined: stage(c+1) in flight while emitting c.
        stage_async(0, 0);
        __syncthreads();                       // drains vmcnt -> buf0 ready
        for (int c = 0; c < NCHUNK; c++) {
            const int b = c & 1;
            if (c + 1 < NCHUNK) stage_async(c + 1, b ^ 1);
            emit_chunk(c, b);
            __syncthreads();                   // all reads of b done + buf b^1 landed
        }
    } else {
        // Last bucket: only 81 valid cols; guarded non-async path (4 blocks total).
        const int limit = VOCAB - v0;
        for (int c = 0; c < NCHUNK; c++) {
            const int dbase = q * 256 + c * DCHUNK;
            for (int r = 0; r < DCHUNK; r++)
                for (int col = tid; col < limit; col += 256)
                    tile[0][r][col] = W[(size_t)(dbase + r) * VOCAB + v0 + col];
            __syncthreads();
            emit_chunk(c, 0);
            __syncthreads();
        }
    }
}

extern "C" void kernel_launch(void* const* d_in, const int* in_sizes, int n_in,
                              void* d_out, int out_size, void* d_ws, size_t ws_size,
                              hipStream_t stream) {
    const int*   ids = (const int*)d_in[0];    // [B*S] = 16384
    const float* W   = (const float*)d_in[1];  // [1024, 50257]
    float*       out = (float*)d_out;
    int*         ws  = (int*)d_ws;

    const int n_tokens = in_sizes[0];

    hist_kernel<<<HBLK, 256, 0, stream>>>(ids, ws, n_tokens);
    scan_kernel<<<1, 256, 0, stream>>>(ws);
    scatter_kernel<<<HBLK, 256, 0, stream>>>(ids, ws, n_tokens);

    dim3 grid(NB, 4);                          // 788 blocks
    emit_kernel<<<grid, 256, 0, stream>>>(W, ws, out);
}